// Round 1
// baseline (1703.476 us; speedup 1.0000x reference)
//
#include <hip/hip_runtime.h>

#define L_TOT 3072
#define DM 512
#define DIN 1024
#define NST 8
#define NB 8
#define NCHUNK 4
#define CHUNK 768

// ---------------- Generic fp32 SGEMM: C = A(MxK) * Bw(NxK)^T (+bias) ----------------
// Output row remapping for the concat case:
//   C_row_off = out_base + (r / rows_per_batch)*out_batch_stride + (r % rows_per_batch)*out_row_stride
#define BM 128
#define BN 128
#define BK 8
__global__ __launch_bounds__(256) void sgemm_tn(
    const float* __restrict__ A, int lda,
    const float* __restrict__ Bw, int ldb,
    float* __restrict__ C,
    int M, int N, int K,
    const float* __restrict__ bias,
    int rows_per_batch, long out_batch_stride, int out_row_stride, long out_base)
{
    __shared__ float As[BK][BM];
    __shared__ float Bs[BK][BN];
    int bm = blockIdx.x * BM;
    int bn = blockIdx.y * BN;
    int tid = threadIdx.x;
    int tm = (tid >> 4) * 8;
    int tn = (tid & 15) * 8;
    int arow = tid >> 1;
    int acol = (tid & 1) * 4;

    float acc[8][8] = {};

    for (int k0 = 0; k0 < K; k0 += BK) {
        float4 av = make_float4(0.f, 0.f, 0.f, 0.f);
        int gra = bm + arow;
        if (gra < M) av = *(const float4*)(A + (long)gra * lda + k0 + acol);
        As[acol + 0][arow] = av.x; As[acol + 1][arow] = av.y;
        As[acol + 2][arow] = av.z; As[acol + 3][arow] = av.w;

        float4 bv = make_float4(0.f, 0.f, 0.f, 0.f);
        int grb = bn + arow;
        if (grb < N) bv = *(const float4*)(Bw + (long)grb * ldb + k0 + acol);
        Bs[acol + 0][arow] = bv.x; Bs[acol + 1][arow] = bv.y;
        Bs[acol + 2][arow] = bv.z; Bs[acol + 3][arow] = bv.w;
        __syncthreads();

        #pragma unroll
        for (int kk = 0; kk < BK; ++kk) {
            float4 a0 = *(const float4*)&As[kk][tm];
            float4 a1 = *(const float4*)&As[kk][tm + 4];
            float4 b0 = *(const float4*)&Bs[kk][tn];
            float4 b1 = *(const float4*)&Bs[kk][tn + 4];
            float a[8] = {a0.x, a0.y, a0.z, a0.w, a1.x, a1.y, a1.z, a1.w};
            float b[8] = {b0.x, b0.y, b0.z, b0.w, b1.x, b1.y, b1.z, b1.w};
            #pragma unroll
            for (int i = 0; i < 8; i++)
                #pragma unroll
                for (int j = 0; j < 8; j++)
                    acc[i][j] = fmaf(a[i], b[j], acc[i][j]);
        }
        __syncthreads();
    }

    #pragma unroll
    for (int i = 0; i < 8; i++) {
        int r = bm + tm + i;
        if (r >= M) continue;
        long crow = out_base + (long)(r / rows_per_batch) * out_batch_stride
                  + (long)(r % rows_per_batch) * out_row_stride;
        #pragma unroll
        for (int j = 0; j < 8; j++) {
            int c = bn + tn + j;
            if (c < N) {
                float v = acc[i][j];
                if (bias) v += bias[c];
                C[crow + c] = v;
            }
        }
    }
}

// ---------------- z at last position only: z[b,d] = x[b,L-1,:] . in_proj_w[1024+d,:] ----------------
__global__ __launch_bounds__(256) void z_last_kernel(
    const float* __restrict__ x, const float* __restrict__ in_proj_w,
    float* __restrict__ z_last)
{
    int b = blockIdx.x;
    int tid = threadIdx.x;
    __shared__ float xs[DM];
    for (int i = tid; i < DM; i += 256) xs[i] = x[((long)(b * L_TOT + (L_TOT - 1))) * DM + i];
    __syncthreads();
    for (int d = tid; d < DIN; d += 256) {
        const float* w = in_proj_w + (long)(DIN + d) * DM;
        float s = 0.f;
        for (int k = 0; k < DM; k += 4) {
            float4 wv = *(const float4*)(w + k);
            s = fmaf(xs[k], wv.x, s); s = fmaf(xs[k + 1], wv.y, s);
            s = fmaf(xs[k + 2], wv.z, s); s = fmaf(xs[k + 3], wv.w, s);
        }
        z_last[b * DIN + d] = s;
    }
}

// ---------------- causal depthwise conv (k=4) + silu ----------------
__global__ __launch_bounds__(256) void conv_silu_kernel(
    const float* __restrict__ xh, const float* __restrict__ conv_w,
    const float* __restrict__ conv_b, float* __restrict__ xc)
{
    int blk = blockIdx.x;            // b*L + l
    int b = blk / L_TOT;
    int l = blk % L_TOT;
    int tid = threadIdx.x;
    for (int d = tid; d < DIN; d += 256) {
        float s = conv_b[d];
        #pragma unroll
        for (int j = 0; j < 4; j++) {
            int ls = l - 3 + j;
            if (ls >= 0) s = fmaf(xh[((long)(b * L_TOT + ls)) * DIN + d], conv_w[d * 4 + j], s);
        }
        float sig = 1.f / (1.f + __expf(-s));
        xc[((long)(b * L_TOT + l)) * DIN + d] = s * sig;
    }
}

// ---------------- dt projection (K=32) + bias + softplus -> delta ----------------
#define DT_TILE_L 16
__global__ __launch_bounds__(256) void dt_softplus_kernel(
    const float* __restrict__ x_dbl, const float* __restrict__ dtw,
    const float* __restrict__ dtb, float* __restrict__ delta)
{
    __shared__ float xs[DT_TILE_L][32];
    long row0 = (long)blockIdx.x * DT_TILE_L;
    int tid = threadIdx.x;
    for (int i = tid; i < DT_TILE_L * 32; i += 256) {
        int r = i >> 5, k = i & 31;
        xs[r][k] = x_dbl[(row0 + r) * 48 + k];
    }
    __syncthreads();
    for (int d = tid; d < DIN; d += 256) {
        float w[32];
        #pragma unroll
        for (int k = 0; k < 32; k++) w[k] = dtw[d * 32 + k];
        float bias = dtb[d];
        for (int r = 0; r < DT_TILE_L; r++) {
            float s = bias;
            #pragma unroll
            for (int k = 0; k < 32; k++) s = fmaf(xs[r][k], w[k], s);
            float sp = fmaxf(s, 0.f) + log1pf(__expf(-fabsf(s)));
            delta[(row0 + r) * DIN + d] = sp;
        }
    }
}

// ---------------- per-chunk delta sums ----------------
__global__ __launch_bounds__(64) void chunk_sum_kernel(
    const float* __restrict__ delta, float* __restrict__ csum)
{
    int blk = blockIdx.x;            // b(8) x c(4) x dblk(16)
    int dblk = blk & 15;
    int c = (blk >> 4) & 3;
    int b = blk >> 6;
    int d = dblk * 64 + threadIdx.x;
    float s = 0.f;
    for (int t = c * CHUNK; t < (c + 1) * CHUNK; ++t)
        s += delta[((long)(b * L_TOT + t)) * DIN + d];
    csum[(b * NCHUNK + c) * DIN + d] = s;
}

// ---------------- chunked suffix-scan reduction ----------------
// h_final[n] = sum_t delta_t*u_t*B_t[n]*exp(A_n * S_t), S_t = suffix-sum of delta (exclusive)
__global__ __launch_bounds__(64) void scan_chunk_kernel(
    const float* __restrict__ delta, const float* __restrict__ xc,
    const float* __restrict__ x_dbl, const float* __restrict__ A_log,
    const float* __restrict__ csum, float* __restrict__ pacc)
{
    int blk = blockIdx.x;            // b(8) x c(4) x dblk(16)
    int dblk = blk & 15;
    int c = (blk >> 4) & 3;
    int b = blk >> 6;
    int d = dblk * 64 + threadIdx.x;

    float a[NST];
    #pragma unroll
    for (int n = 0; n < NST; n++) a[n] = -__expf(A_log[d * NST + n]);

    float S = 0.f;
    for (int cc = c + 1; cc < NCHUNK; ++cc) S += csum[(b * NCHUNK + cc) * DIN + d];

    float acc[NST] = {};
    int t0 = c * CHUNK;
    for (int t = t0 + CHUNK - 1; t >= t0; --t) {
        long idx = ((long)(b * L_TOT + t)) * DIN + d;
        float dl = delta[idx];
        float u = xc[idx];
        const float* xb = x_dbl + ((long)(b * L_TOT + t)) * 48 + 32;
        float w = dl * u;
        #pragma unroll
        for (int n = 0; n < NST; n++)
            acc[n] = fmaf(w * xb[n], __expf(a[n] * S), acc[n]);
        S += dl;
        if (((t & 31) == 0) && __all(S > 95.0f)) break;   // exp(A_n*S)==0 for all remaining t
    }
    #pragma unroll
    for (int n = 0; n < NST; n++)
        pacc[((b * NCHUNK + c) * NST + n) * DIN + d] = acc[n];
}

// ---------------- finalize: y_last[b,d] ----------------
__global__ __launch_bounds__(256) void scan_finalize_kernel(
    const float* __restrict__ pacc, const float* __restrict__ x_dbl,
    const float* __restrict__ delta, const float* __restrict__ xc,
    const float* __restrict__ Dp, const float* __restrict__ z_last,
    float* __restrict__ y_last)
{
    int g = blockIdx.x * 256 + threadIdx.x;    // 8192
    int b = g >> 10;
    int d = g & 1023;
    const float* xd = x_dbl + ((long)(b * L_TOT + (L_TOT - 1))) * 48;
    float y = 0.f, bc = 0.f;
    #pragma unroll
    for (int n = 0; n < NST; n++) {
        float accs = 0.f;
        #pragma unroll
        for (int c = 0; c < NCHUNK; c++)
            accs += pacc[((b * NCHUNK + c) * NST + n) * DIN + d];
        float Bn = xd[32 + n], Cn = xd[40 + n];
        y += accs * Cn;
        bc += Bn * Cn;
    }
    long idxL = ((long)(b * L_TOT + (L_TOT - 1))) * DIN + d;
    float dL = delta[idxL], uL = xc[idxL];
    y += dL * uL * bc;            // backward-scan first step at original l=L-1
    y += 2.f * uL * Dp[d];        // u*Dp from both directions
    float z = z_last[g];
    y_last[g] = y * (z / (1.f + __expf(-z)));
}

// ---------------- out_proj(last) + LayerNorm + ReLU + head ----------------
__global__ __launch_bounds__(256) void head_kernel(
    const float* __restrict__ y_last, const float* __restrict__ out_proj_w,
    const float* __restrict__ ln_g, const float* __restrict__ ln_b,
    const float* __restrict__ head_w, const float* __restrict__ head_b,
    float* __restrict__ out)
{
    int b = blockIdx.x;
    int tid = threadIdx.x;
    __shared__ float ys[DIN];
    __shared__ float h[DM];
    __shared__ float red[256];
    for (int i = tid; i < DIN; i += 256) ys[i] = y_last[b * DIN + i];
    __syncthreads();
    for (int e = tid; e < DM; e += 256) {
        const float* w = out_proj_w + (long)e * DIN;
        float s = 0.f;
        for (int k = 0; k < DIN; k += 4) {
            float4 wv = *(const float4*)(w + k);
            s = fmaf(ys[k], wv.x, s); s = fmaf(ys[k + 1], wv.y, s);
            s = fmaf(ys[k + 2], wv.z, s); s = fmaf(ys[k + 3], wv.w, s);
        }
        h[e] = s;
    }
    __syncthreads();
    red[tid] = h[tid] + h[tid + 256];
    __syncthreads();
    for (int s = 128; s > 0; s >>= 1) { if (tid < s) red[tid] += red[tid + s]; __syncthreads(); }
    float mu = red[0] / (float)DM;
    __syncthreads();
    float d0 = h[tid] - mu, d1 = h[tid + 256] - mu;
    red[tid] = d0 * d0 + d1 * d1;
    __syncthreads();
    for (int s = 128; s > 0; s >>= 1) { if (tid < s) red[tid] += red[tid + s]; __syncthreads(); }
    float inv = 1.f / sqrtf(red[0] / (float)DM + 1e-5f);
    __syncthreads();
    for (int e = tid; e < DM; e += 256) {
        float v = (h[e] - mu) * inv * ln_g[e] + ln_b[e];
        h[e] = fmaxf(v, 0.f);
    }
    __syncthreads();
    if (tid < 160) {
        int e2 = tid >> 4, pp = tid & 15;
        float s = 0.f;
        for (int k = pp * 32; k < pp * 32 + 32; k++) s += h[k] * head_w[e2 * DM + k];
        red[tid] = s;
    }
    __syncthreads();
    if (tid < 10) {
        float s = 0.f;
        for (int i = 0; i < 16; i++) s += red[tid * 16 + i];
        out[b * 10 + tid] = s + head_b[tid];
    }
}

extern "C" void kernel_launch(void* const* d_in, const int* in_sizes, int n_in,
                              void* d_out, int out_size, void* d_ws, size_t ws_size,
                              hipStream_t stream) {
    const float* feat0 = (const float*)d_in[0];
    const float* feat1 = (const float*)d_in[1];
    const float* feat2 = (const float*)d_in[2];
    const float* aw0 = (const float*)d_in[3];
    const float* ab0 = (const float*)d_in[4];
    const float* aw1 = (const float*)d_in[5];
    const float* ab1 = (const float*)d_in[6];
    const float* aw2 = (const float*)d_in[7];
    const float* ab2 = (const float*)d_in[8];
    const float* in_proj_w = (const float*)d_in[9];
    const float* conv_w = (const float*)d_in[10];
    const float* conv_b = (const float*)d_in[11];
    const float* x_proj_w = (const float*)d_in[12];
    const float* dt_proj_w = (const float*)d_in[13];
    const float* dt_proj_b = (const float*)d_in[14];
    const float* A_log = (const float*)d_in[15];
    // d_in[16] = A_b_log: unused (backward scan's dA multiplies h0=0)
    const float* Dp = (const float*)d_in[17];
    const float* out_proj_w = (const float*)d_in[18];
    const float* ln_g = (const float*)d_in[19];
    const float* ln_b = (const float*)d_in[20];
    const float* head_w = (const float*)d_in[21];
    const float* head_b = (const float*)d_in[22];
    float* out = (float*)d_out;

    char* ws = (char*)d_ws;
    const size_t SZ_BLD = (size_t)NB * L_TOT * DIN * 4;   // 100663296
    float* xh    = (float*)(ws + 0);                      // [0, 100MB) ; reused by delta
    float* xc    = (float*)(ws + SZ_BLD);                 // [100MB, 200MB)
    float* x     = (float*)(ws + 2 * SZ_BLD);             // [200MB, 250MB) ; reused by x_dbl
    float* x_dbl = x;                                     // x dead after in_proj + z_last
    float* delta = xh;                                    // xh dead after conv
    char*  tail  = ws + 2 * SZ_BLD + (size_t)NB * L_TOT * DM * 4;
    float* z_last = (float*)(tail);
    float* y_last = (float*)(tail + 32768);
    float* csum   = (float*)(tail + 65536);
    float* pacc   = (float*)(tail + 65536 + 131072);

    // 1. feature projections -> x (B, 3072, 512); segment s occupies rows [s*1024,(s+1)*1024)
    {
        dim3 g0(8192 / BM, DM / BN);
        sgemm_tn<<<g0, 256, 0, stream>>>(feat0, 768, aw0, 768, x, 8192, DM, 768, ab0,
                                         1024, (long)L_TOT * DM, DM, 0L * 1024 * DM);
        sgemm_tn<<<g0, 256, 0, stream>>>(feat1, 1024, aw1, 1024, x, 8192, DM, 1024, ab1,
                                         1024, (long)L_TOT * DM, DM, 1L * 1024 * DM);
        sgemm_tn<<<g0, 256, 0, stream>>>(feat2, 512, aw2, 512, x, 8192, DM, 512, ab2,
                                         1024, (long)L_TOT * DM, DM, 2L * 1024 * DM);
    }
    // 2. in_proj (xh half) -> xh (b,l,d); z at last position only
    {
        dim3 g(NB * L_TOT / BM, DIN / BN);
        sgemm_tn<<<g, 256, 0, stream>>>(x, DM, in_proj_w, DM, xh, NB * L_TOT, DIN, DM, nullptr,
                                        NB * L_TOT, 0, DIN, 0);
        z_last_kernel<<<NB, 256, 0, stream>>>(x, in_proj_w, z_last);
    }
    // 3. causal depthwise conv + silu -> xc
    conv_silu_kernel<<<NB * L_TOT, 256, 0, stream>>>(xh, conv_w, conv_b, xc);
    // 4. x_dbl = xc @ x_proj_w^T  (N=48)
    {
        dim3 g(NB * L_TOT / BM, 1);
        sgemm_tn<<<g, 256, 0, stream>>>(xc, DIN, x_proj_w, DIN, x_dbl, NB * L_TOT, 48, DIN, nullptr,
                                        NB * L_TOT, 0, 48, 0);
    }
    // 5. delta = softplus(x_dbl[:, :32] @ dt_proj_w^T + dt_proj_b)   (overwrites xh region)
    dt_softplus_kernel<<<NB * L_TOT / DT_TILE_L, 256, 0, stream>>>(x_dbl, dt_proj_w, dt_proj_b, delta);
    // 6. scan: chunk sums -> chunked suffix reduction -> finalize
    chunk_sum_kernel<<<NB * NCHUNK * 16, 64, 0, stream>>>(delta, csum);
    scan_chunk_kernel<<<NB * NCHUNK * 16, 64, 0, stream>>>(delta, xc, x_dbl, A_log, csum, pacc);
    scan_finalize_kernel<<<NB * DIN / 256, 256, 0, stream>>>(pacc, x_dbl, delta, xc, Dp, z_last, y_last);
    // 7. out_proj(last) + LN + ReLU + head
    head_kernel<<<NB, 256, 0, stream>>>(y_last, out_proj_w, ln_g, ln_b, head_w, head_b, out);
}

// Round 2
// 1342.889 us; speedup vs baseline: 1.2685x; 1.2685x over previous
//
#include <hip/hip_runtime.h>

#define L_TOT 3072
#define DM 512
#define DIN 1024
#define NST 8
#define NB 8
#define NCHUNK 48
#define CHUNK 64
#define S_CUT 18.0f

// ---------------- Generic fp32 SGEMM: C = A(MxK) * Bw(NxK)^T (+bias) ----------------
#define BM 128
#define BN 128
#define BK 8
__global__ __launch_bounds__(256) void sgemm_tn(
    const float* __restrict__ A, int lda,
    const float* __restrict__ Bw, int ldb,
    float* __restrict__ C,
    int M, int N, int K,
    const float* __restrict__ bias,
    int rows_per_batch, long out_batch_stride, int out_row_stride, long out_base)
{
    __shared__ float As[BK][BM];
    __shared__ float Bs[BK][BN];
    int bm = blockIdx.x * BM;
    int bn = blockIdx.y * BN;
    int tid = threadIdx.x;
    int tm = (tid >> 4) * 8;
    int tn = (tid & 15) * 8;
    int arow = tid >> 1;
    int acol = (tid & 1) * 4;

    float acc[8][8] = {};

    for (int k0 = 0; k0 < K; k0 += BK) {
        float4 av = make_float4(0.f, 0.f, 0.f, 0.f);
        int gra = bm + arow;
        if (gra < M) av = *(const float4*)(A + (long)gra * lda + k0 + acol);
        As[acol + 0][arow] = av.x; As[acol + 1][arow] = av.y;
        As[acol + 2][arow] = av.z; As[acol + 3][arow] = av.w;

        float4 bv = make_float4(0.f, 0.f, 0.f, 0.f);
        int grb = bn + arow;
        if (grb < N) bv = *(const float4*)(Bw + (long)grb * ldb + k0 + acol);
        Bs[acol + 0][arow] = bv.x; Bs[acol + 1][arow] = bv.y;
        Bs[acol + 2][arow] = bv.z; Bs[acol + 3][arow] = bv.w;
        __syncthreads();

        #pragma unroll
        for (int kk = 0; kk < BK; ++kk) {
            float4 a0 = *(const float4*)&As[kk][tm];
            float4 a1 = *(const float4*)&As[kk][tm + 4];
            float4 b0 = *(const float4*)&Bs[kk][tn];
            float4 b1 = *(const float4*)&Bs[kk][tn + 4];
            float a[8] = {a0.x, a0.y, a0.z, a0.w, a1.x, a1.y, a1.z, a1.w};
            float b[8] = {b0.x, b0.y, b0.z, b0.w, b1.x, b1.y, b1.z, b1.w};
            #pragma unroll
            for (int i = 0; i < 8; i++)
                #pragma unroll
                for (int j = 0; j < 8; j++)
                    acc[i][j] = fmaf(a[i], b[j], acc[i][j]);
        }
        __syncthreads();
    }

    #pragma unroll
    for (int i = 0; i < 8; i++) {
        int r = bm + tm + i;
        if (r >= M) continue;
        long crow = out_base + (long)(r / rows_per_batch) * out_batch_stride
                  + (long)(r % rows_per_batch) * out_row_stride;
        #pragma unroll
        for (int j = 0; j < 8; j++) {
            int c = bn + tn + j;
            if (c < N) {
                float v = acc[i][j];
                if (bias) v += bias[c];
                C[crow + c] = v;
            }
        }
    }
}

// ---------------- z at last position only ----------------
__global__ __launch_bounds__(256) void z_last_kernel(
    const float* __restrict__ x, const float* __restrict__ in_proj_w,
    float* __restrict__ z_last)
{
    int b = blockIdx.x;
    int tid = threadIdx.x;
    __shared__ float xs[DM];
    for (int i = tid; i < DM; i += 256) xs[i] = x[((long)(b * L_TOT + (L_TOT - 1))) * DM + i];
    __syncthreads();
    for (int d = tid; d < DIN; d += 256) {
        const float* w = in_proj_w + (long)(DIN + d) * DM;
        float s = 0.f;
        for (int k = 0; k < DM; k += 4) {
            float4 wv = *(const float4*)(w + k);
            s = fmaf(xs[k], wv.x, s); s = fmaf(xs[k + 1], wv.y, s);
            s = fmaf(xs[k + 2], wv.z, s); s = fmaf(xs[k + 3], wv.w, s);
        }
        z_last[b * DIN + d] = s;
    }
}

// ---------------- causal depthwise conv (k=4) + silu ----------------
__global__ __launch_bounds__(256) void conv_silu_kernel(
    const float* __restrict__ xh, const float* __restrict__ conv_w,
    const float* __restrict__ conv_b, float* __restrict__ xc)
{
    int blk = blockIdx.x;            // b*L + l
    int b = blk / L_TOT;
    int l = blk % L_TOT;
    int tid = threadIdx.x;
    for (int d = tid; d < DIN; d += 256) {
        float s = conv_b[d];
        #pragma unroll
        for (int j = 0; j < 4; j++) {
            int ls = l - 3 + j;
            if (ls >= 0) s = fmaf(xh[((long)(b * L_TOT + ls)) * DIN + d], conv_w[d * 4 + j], s);
        }
        float sig = 1.f / (1.f + __expf(-s));
        xc[((long)(b * L_TOT + l)) * DIN + d] = s * sig;
    }
}

// ---------------- dt projection (K=32) + bias + softplus -> delta ----------------
#define DT_TILE_L 16
__global__ __launch_bounds__(256) void dt_softplus_kernel(
    const float* __restrict__ x_dbl, const float* __restrict__ dtw,
    const float* __restrict__ dtb, float* __restrict__ delta)
{
    __shared__ float xs[DT_TILE_L][32];
    long row0 = (long)blockIdx.x * DT_TILE_L;
    int tid = threadIdx.x;
    for (int i = tid; i < DT_TILE_L * 32; i += 256) {
        int r = i >> 5, k = i & 31;
        xs[r][k] = x_dbl[(row0 + r) * 48 + k];
    }
    __syncthreads();
    for (int d = tid; d < DIN; d += 256) {
        float w[32];
        #pragma unroll
        for (int k = 0; k < 32; k++) w[k] = dtw[d * 32 + k];
        float bias = dtb[d];
        for (int r = 0; r < DT_TILE_L; r++) {
            float s = bias;
            #pragma unroll
            for (int k = 0; k < 32; k++) s = fmaf(xs[r][k], w[k], s);
            float sp = fmaxf(s, 0.f) + log1pf(__expf(-fabsf(s)));
            delta[(row0 + r) * DIN + d] = sp;
        }
    }
}

// ---------------- per-chunk delta sums (CHUNK=64) ----------------
__global__ __launch_bounds__(64) void chunk_sum_kernel(
    const float* __restrict__ delta, float* __restrict__ csum)
{
    int blk = blockIdx.x;            // b(8) x c(48) x dblk(16)
    int dblk = blk & 15;
    int c = (blk >> 4) % NCHUNK;
    int b = blk / (16 * NCHUNK);
    int d = dblk * 64 + threadIdx.x;
    float s = 0.f;
    #pragma unroll 4
    for (int t = c * CHUNK; t < (c + 1) * CHUNK; ++t)
        s += delta[((long)(b * L_TOT + t)) * DIN + d];
    csum[(b * NCHUNK + c) * DIN + d] = s;
}

// ---------------- chunked suffix-scan reduction, C_last folded in ----------------
// pacc_y[b,c,d] = sum_n C_last[n] * sum_{t in chunk c} delta_t*u_t*B_t[n]*exp(A_n*S_t)
__global__ __launch_bounds__(64) void scan_chunk_kernel(
    const float* __restrict__ delta, const float* __restrict__ xc,
    const float* __restrict__ x_dbl, const float* __restrict__ A_log,
    const float* __restrict__ csum, float* __restrict__ pacc_y)
{
    int blk = blockIdx.x;            // b(8) x c(48) x dblk(16)
    int dblk = blk & 15;
    int c = (blk >> 4) % NCHUNK;
    int b = blk / (16 * NCHUNK);
    int d = dblk * 64 + threadIdx.x;
    long pidx = ((long)(b * NCHUNK + c)) * DIN + d;

    // incoming suffix sum from later chunks
    float S = 0.f;
    bool dead = false;
    for (int cc = c + 1; cc < NCHUNK; ++cc) {
        S += csum[((long)(b * NCHUNK + cc)) * DIN + d];
        if (__all(S > S_CUT)) { dead = true; break; }
    }
    if (dead) { pacc_y[pidx] = 0.f; return; }

    float a[NST];
    #pragma unroll
    for (int n = 0; n < NST; n++) a[n] = -__expf(A_log[d * NST + n]);
    const float* xdl = x_dbl + ((long)(b * L_TOT + (L_TOT - 1))) * 48;
    float Cl[NST];
    #pragma unroll
    for (int n = 0; n < NST; n++) Cl[n] = xdl[40 + n];

    float acc = 0.f;
    int t0 = c * CHUNK;
    for (int t = t0 + CHUNK - 1; t >= t0; --t) {
        long idx = ((long)(b * L_TOT + t)) * DIN + d;
        float dl = delta[idx];
        float u = xc[idx];
        const float* xb = x_dbl + ((long)(b * L_TOT + t)) * 48 + 32;
        float w = dl * u;
        #pragma unroll
        for (int n = 0; n < NST; n++)
            acc = fmaf(w * xb[n] * Cl[n], __expf(a[n] * S), acc);
        S += dl;
        if (((t & 7) == 0) && __all(S > S_CUT)) break;
    }
    pacc_y[pidx] = acc;
}

// ---------------- finalize: y_last[b,d] ----------------
__global__ __launch_bounds__(256) void scan_finalize_kernel(
    const float* __restrict__ pacc_y, const float* __restrict__ x_dbl,
    const float* __restrict__ delta, const float* __restrict__ xc,
    const float* __restrict__ Dp, const float* __restrict__ z_last,
    float* __restrict__ y_last)
{
    int g = blockIdx.x * 256 + threadIdx.x;    // 8192
    int b = g >> 10;
    int d = g & 1023;
    const float* xd = x_dbl + ((long)(b * L_TOT + (L_TOT - 1))) * 48;
    float y = 0.f;
    for (int c = 0; c < NCHUNK; c++)
        y += pacc_y[((long)(b * NCHUNK + c)) * DIN + d];
    float bc = 0.f;
    #pragma unroll
    for (int n = 0; n < NST; n++) bc += xd[32 + n] * xd[40 + n];
    long idxL = ((long)(b * L_TOT + (L_TOT - 1))) * DIN + d;
    float dL = delta[idxL], uL = xc[idxL];
    y += dL * uL * bc;            // backward-scan first step at original l=L-1
    y += 2.f * uL * Dp[d];        // u*Dp from both directions
    float z = z_last[g];
    y_last[g] = y * (z / (1.f + __expf(-z)));
}

// ---------------- out_proj(last) + LayerNorm + ReLU + head ----------------
__global__ __launch_bounds__(256) void head_kernel(
    const float* __restrict__ y_last, const float* __restrict__ out_proj_w,
    const float* __restrict__ ln_g, const float* __restrict__ ln_b,
    const float* __restrict__ head_w, const float* __restrict__ head_b,
    float* __restrict__ out)
{
    int b = blockIdx.x;
    int tid = threadIdx.x;
    __shared__ float ys[DIN];
    __shared__ float h[DM];
    __shared__ float red[256];
    for (int i = tid; i < DIN; i += 256) ys[i] = y_last[b * DIN + i];
    __syncthreads();
    for (int e = tid; e < DM; e += 256) {
        const float* w = out_proj_w + (long)e * DIN;
        float s = 0.f;
        for (int k = 0; k < DIN; k += 4) {
            float4 wv = *(const float4*)(w + k);
            s = fmaf(ys[k], wv.x, s); s = fmaf(ys[k + 1], wv.y, s);
            s = fmaf(ys[k + 2], wv.z, s); s = fmaf(ys[k + 3], wv.w, s);
        }
        h[e] = s;
    }
    __syncthreads();
    red[tid] = h[tid] + h[tid + 256];
    __syncthreads();
    for (int s = 128; s > 0; s >>= 1) { if (tid < s) red[tid] += red[tid + s]; __syncthreads(); }
    float mu = red[0] / (float)DM;
    __syncthreads();
    float d0 = h[tid] - mu, d1 = h[tid + 256] - mu;
    red[tid] = d0 * d0 + d1 * d1;
    __syncthreads();
    for (int s = 128; s > 0; s >>= 1) { if (tid < s) red[tid] += red[tid + s]; __syncthreads(); }
    float inv = 1.f / sqrtf(red[0] / (float)DM + 1e-5f);
    __syncthreads();
    for (int e = tid; e < DM; e += 256) {
        float v = (h[e] - mu) * inv * ln_g[e] + ln_b[e];
        h[e] = fmaxf(v, 0.f);
    }
    __syncthreads();
    if (tid < 160) {
        int e2 = tid >> 4, pp = tid & 15;
        float s = 0.f;
        for (int k = pp * 32; k < pp * 32 + 32; k++) s += h[k] * head_w[e2 * DM + k];
        red[tid] = s;
    }
    __syncthreads();
    if (tid < 10) {
        float s = 0.f;
        for (int i = 0; i < 16; i++) s += red[tid * 16 + i];
        out[b * 10 + tid] = s + head_b[tid];
    }
}

extern "C" void kernel_launch(void* const* d_in, const int* in_sizes, int n_in,
                              void* d_out, int out_size, void* d_ws, size_t ws_size,
                              hipStream_t stream) {
    const float* feat0 = (const float*)d_in[0];
    const float* feat1 = (const float*)d_in[1];
    const float* feat2 = (const float*)d_in[2];
    const float* aw0 = (const float*)d_in[3];
    const float* ab0 = (const float*)d_in[4];
    const float* aw1 = (const float*)d_in[5];
    const float* ab1 = (const float*)d_in[6];
    const float* aw2 = (const float*)d_in[7];
    const float* ab2 = (const float*)d_in[8];
    const float* in_proj_w = (const float*)d_in[9];
    const float* conv_w = (const float*)d_in[10];
    const float* conv_b = (const float*)d_in[11];
    const float* x_proj_w = (const float*)d_in[12];
    const float* dt_proj_w = (const float*)d_in[13];
    const float* dt_proj_b = (const float*)d_in[14];
    const float* A_log = (const float*)d_in[15];
    // d_in[16] = A_b_log: unused (backward scan's dA multiplies h0=0)
    const float* Dp = (const float*)d_in[17];
    const float* out_proj_w = (const float*)d_in[18];
    const float* ln_g = (const float*)d_in[19];
    const float* ln_b = (const float*)d_in[20];
    const float* head_w = (const float*)d_in[21];
    const float* head_b = (const float*)d_in[22];
    float* out = (float*)d_out;

    char* ws = (char*)d_ws;
    const size_t SZ_BLD = (size_t)NB * L_TOT * DIN * 4;   // 100663296
    float* xh    = (float*)(ws + 0);                      // reused by delta
    float* xc    = (float*)(ws + SZ_BLD);
    float* x     = (float*)(ws + 2 * SZ_BLD);             // 50.3MB; first 4.7MB reused by x_dbl
    float* x_dbl = x;
    float* delta = xh;
    char*  tail  = ws + 2 * SZ_BLD + (size_t)8 * 1024 * 1024;  // after x_dbl's 4.7MB
    float* z_last = (float*)(tail);
    float* y_last = (float*)(tail + 32768);
    float* csum   = (float*)(tail + 65536);                       // 1.57MB
    float* pacc_y = (float*)(tail + 65536 + 1572864);             // 1.57MB

    // 1. feature projections -> x (B, 3072, 512)
    {
        dim3 g0(8192 / BM, DM / BN);
        sgemm_tn<<<g0, 256, 0, stream>>>(feat0, 768, aw0, 768, x, 8192, DM, 768, ab0,
                                         1024, (long)L_TOT * DM, DM, 0L * 1024 * DM);
        sgemm_tn<<<g0, 256, 0, stream>>>(feat1, 1024, aw1, 1024, x, 8192, DM, 1024, ab1,
                                         1024, (long)L_TOT * DM, DM, 1L * 1024 * DM);
        sgemm_tn<<<g0, 256, 0, stream>>>(feat2, 512, aw2, 512, x, 8192, DM, 512, ab2,
                                         1024, (long)L_TOT * DM, DM, 2L * 1024 * DM);
    }
    // 2. in_proj (xh half) -> xh; z at last position only
    {
        dim3 g(NB * L_TOT / BM, DIN / BN);
        sgemm_tn<<<g, 256, 0, stream>>>(x, DM, in_proj_w, DM, xh, NB * L_TOT, DIN, DM, nullptr,
                                        NB * L_TOT, 0, DIN, 0);
        z_last_kernel<<<NB, 256, 0, stream>>>(x, in_proj_w, z_last);
    }
    // 3. causal depthwise conv + silu -> xc
    conv_silu_kernel<<<NB * L_TOT, 256, 0, stream>>>(xh, conv_w, conv_b, xc);
    // 4. x_dbl = xc @ x_proj_w^T  (N=48)
    {
        dim3 g(NB * L_TOT / BM, 1);
        sgemm_tn<<<g, 256, 0, stream>>>(xc, DIN, x_proj_w, DIN, x_dbl, NB * L_TOT, 48, DIN, nullptr,
                                        NB * L_TOT, 0, 48, 0);
    }
    // 5. delta = softplus(...) (overwrites xh region)
    dt_softplus_kernel<<<NB * L_TOT / DT_TILE_L, 256, 0, stream>>>(x_dbl, dt_proj_w, dt_proj_b, delta);
    // 6. scan: chunk sums -> chunked suffix reduction (early-exit) -> finalize
    chunk_sum_kernel<<<NB * NCHUNK * 16, 64, 0, stream>>>(delta, csum);
    scan_chunk_kernel<<<NB * NCHUNK * 16, 64, 0, stream>>>(delta, xc, x_dbl, A_log, csum, pacc_y);
    scan_finalize_kernel<<<NB * DIN / 256, 256, 0, stream>>>(pacc_y, x_dbl, delta, xc, Dp, z_last, y_last);
    // 7. out_proj(last) + LN + ReLU + head
    head_kernel<<<NB, 256, 0, stream>>>(y_last, out_proj_w, ln_g, ln_b, head_w, head_b, out);
}

// Round 3
// 556.391 us; speedup vs baseline: 3.0617x; 2.4136x over previous
//
#include <hip/hip_runtime.h>

#define L_TOT 3072
#define DM 512
#define DIN 1024
#define NST 8
#define NB 8
#define NCHUNK 48
#define CHUNK 64
#define S_CUT 18.0f

typedef __attribute__((ext_vector_type(8))) short bf16x8;
typedef __attribute__((ext_vector_type(4))) float f32x4;

__device__ __forceinline__ float bf2f(ushort u) {
    union { uint i; float f; } c; c.i = ((uint)u) << 16; return c.f;
}
__device__ __forceinline__ ushort f2bf(float f) {
    union { float f; uint i; } c; c.f = f;
    uint x = c.i;
    uint r = x + 0x7fffu + ((x >> 16) & 1u);
    return (ushort)(r >> 16);
}
__device__ __forceinline__ void async16(const void* g, void* l) {
    __builtin_amdgcn_global_load_lds((const __attribute__((address_space(1))) char*)g,
                                     (__attribute__((address_space(3))) char*)l, 16, 0, 0);
}

// ---------------- fp32 -> bf16 conversion (fused, all tensors) ----------------
__device__ __forceinline__ void cvt8(const float* s, ushort* d) {
    float4 a = *(const float4*)s;
    float4 b = *(const float4*)(s + 4);
    ushort o[8] = {f2bf(a.x), f2bf(a.y), f2bf(a.z), f2bf(a.w),
                   f2bf(b.x), f2bf(b.y), f2bf(b.z), f2bf(b.w)};
    *(uint4*)d = *(uint4*)o;
}

__global__ __launch_bounds__(256) void convert_kernel(
    const float* __restrict__ f0, const float* __restrict__ f1, const float* __restrict__ f2,
    const float* __restrict__ w0, const float* __restrict__ w1, const float* __restrict__ w2,
    const float* __restrict__ ipw, const float* __restrict__ xpw,
    ushort* __restrict__ d_f0, ushort* __restrict__ d_f1, ushort* __restrict__ d_f2,
    ushort* __restrict__ d_w0, ushort* __restrict__ d_w1, ushort* __restrict__ d_w2,
    ushort* __restrict__ d_ipw, ushort* __restrict__ d_xpw)
{
    long e = ((long)blockIdx.x * 256 + threadIdx.x) * 8;
    if (e < 6291456)  { cvt8(f0 + e, d_f0 + e); return; }
    e -= 6291456;
    if (e < 8388608)  { cvt8(f1 + e, d_f1 + e); return; }
    e -= 8388608;
    if (e < 4194304)  { cvt8(f2 + e, d_f2 + e); return; }
    e -= 4194304;
    if (e < 393216)   { cvt8(w0 + e, d_w0 + e); return; }
    e -= 393216;
    if (e < 524288)   { cvt8(w1 + e, d_w1 + e); return; }
    e -= 524288;
    if (e < 262144)   { cvt8(w2 + e, d_w2 + e); return; }
    e -= 262144;
    if (e < 524288)   { cvt8(ipw + e, d_ipw + e); return; }
    e -= 524288;
    { // x_proj_w padded 48x1024 -> 64x1024 (zero rows 48..63)
        int row = (int)(e >> 10), col = (int)(e & 1023);
        if (row < 48) cvt8(xpw + row * 1024 + col, d_xpw + e);
        else { uint4 z = make_uint4(0, 0, 0, 0); *(uint4*)(d_xpw + e) = z; }
    }
}

// ---------------- bf16 MFMA GEMM: C = A(MxK) * Bw(NxK)^T (+bias) ----------------
// m97 structure: global_load_lds 16B staging, [rows][BK] linear LDS, 16x16x32 MFMA.
template<int BM, int BN, int NWM, int NWN, int FM, int FN, bool OUT_BF16>
__global__ __launch_bounds__(256) void gemm_mfma(
    const ushort* __restrict__ A, int lda,
    const ushort* __restrict__ Bw, int ldb,
    void* __restrict__ C, int ldc,
    int M, int K,
    const float* __restrict__ bias,
    int rows_per_batch, long out_batch_stride, long out_base)
{
    constexpr int BK = 32;
    __shared__ ushort As[BM * BK];
    __shared__ ushort Bs[BN * BK];
    int tid = threadIdx.x;
    int lane = tid & 63;
    int wid = tid >> 6;
    int bm = blockIdx.x * BM;
    int bn = blockIdx.y * BN;
    int wm = (wid / NWN) * FM * 16;
    int wn = (wid % NWN) * FN * 16;
    int trow = tid >> 2;              // staging: 4096B = 64 rows of 64B
    int tcol = (tid & 3) * 8;

    f32x4 zero = {0.f, 0.f, 0.f, 0.f};
    f32x4 acc[FM][FN];
    #pragma unroll
    for (int m = 0; m < FM; m++)
        #pragma unroll
        for (int n = 0; n < FN; n++) acc[m][n] = zero;

    constexpr int nA = BM * BK * 2 / 4096;
    constexpr int nB = BN * BK * 2 / 4096;

    for (int k0 = 0; k0 < K; k0 += BK) {
        __syncthreads();
        #pragma unroll
        for (int i = 0; i < nA; i++) {
            int row = i * 64 + trow;
            async16(A + (size_t)(bm + row) * lda + k0 + tcol, (char*)As + i * 4096 + tid * 16);
        }
        #pragma unroll
        for (int i = 0; i < nB; i++) {
            int row = i * 64 + trow;
            async16(Bw + (size_t)(bn + row) * ldb + k0 + tcol, (char*)Bs + i * 4096 + tid * 16);
        }
        __syncthreads();

        bf16x8 af[FM], bfr[FN];
        #pragma unroll
        for (int m = 0; m < FM; m++)
            af[m] = *(const bf16x8*)(As + (wm + m * 16 + (lane & 15)) * BK + (lane >> 4) * 8);
        #pragma unroll
        for (int n = 0; n < FN; n++)
            bfr[n] = *(const bf16x8*)(Bs + (wn + n * 16 + (lane & 15)) * BK + (lane >> 4) * 8);
        #pragma unroll
        for (int m = 0; m < FM; m++)
            #pragma unroll
            for (int n = 0; n < FN; n++)
                acc[m][n] = __builtin_amdgcn_mfma_f32_16x16x32_bf16(af[m], bfr[n], acc[m][n], 0, 0, 0);
    }

    #pragma unroll
    for (int m = 0; m < FM; m++) {
        int rbase = bm + wm + m * 16 + (lane >> 4) * 4;
        #pragma unroll
        for (int n = 0; n < FN; n++) {
            int c_ = bn + wn + n * 16 + (lane & 15);
            float bv = bias ? bias[c_] : 0.f;
            #pragma unroll
            for (int r = 0; r < 4; r++) {
                int r_ = rbase + r;
                long row_off = out_base + (long)(r_ / rows_per_batch) * out_batch_stride
                             + (long)(r_ % rows_per_batch) * ldc;
                float v = acc[m][n][r] + bv;
                if constexpr (OUT_BF16) ((ushort*)C)[row_off + c_] = f2bf(v);
                else                    ((float*)C)[row_off + c_] = v;
            }
        }
    }
}

// ---------------- z at last position only (x in bf16) ----------------
__global__ __launch_bounds__(256) void z_last_kernel(
    const ushort* __restrict__ x, const float* __restrict__ in_proj_w,
    float* __restrict__ z_last)
{
    int b = blockIdx.x;
    int tid = threadIdx.x;
    __shared__ float xs[DM];
    for (int i = tid; i < DM; i += 256)
        xs[i] = bf2f(x[((size_t)(b * L_TOT + (L_TOT - 1))) * DM + i]);
    __syncthreads();
    for (int d = tid; d < DIN; d += 256) {
        const float* w = in_proj_w + (size_t)(DIN + d) * DM;
        float s = 0.f;
        for (int k = 0; k < DM; k += 4) {
            float4 wv = *(const float4*)(w + k);
            s = fmaf(xs[k], wv.x, s); s = fmaf(xs[k + 1], wv.y, s);
            s = fmaf(xs[k + 2], wv.z, s); s = fmaf(xs[k + 3], wv.w, s);
        }
        z_last[b * DIN + d] = s;
    }
}

// ---------------- causal depthwise conv (k=4) + silu, bf16 in/out ----------------
__global__ __launch_bounds__(128) void conv_silu_kernel(
    const ushort* __restrict__ xh, const float* __restrict__ conv_w,
    const float* __restrict__ conv_b, ushort* __restrict__ xc)
{
    int blk = blockIdx.x;            // b*L + l
    int b = blk / L_TOT;
    int l = blk % L_TOT;
    int d0 = threadIdx.x * 8;
    float acc[8];
    {
        float4 b0 = *(const float4*)(conv_b + d0);
        float4 b1 = *(const float4*)(conv_b + d0 + 4);
        acc[0] = b0.x; acc[1] = b0.y; acc[2] = b0.z; acc[3] = b0.w;
        acc[4] = b1.x; acc[5] = b1.y; acc[6] = b1.z; acc[7] = b1.w;
    }
    float w[8][4];
    #pragma unroll
    for (int i = 0; i < 8; i++) {
        float4 wv = *(const float4*)(conv_w + (d0 + i) * 4);
        w[i][0] = wv.x; w[i][1] = wv.y; w[i][2] = wv.z; w[i][3] = wv.w;
    }
    #pragma unroll
    for (int j = 0; j < 4; j++) {
        int ls = l - 3 + j;
        if (ls < 0) continue;
        uint4 v = *(const uint4*)(xh + ((size_t)(b * L_TOT + ls)) * DIN + d0);
        const ushort* pv = (const ushort*)&v;
        #pragma unroll
        for (int i = 0; i < 8; i++)
            acc[i] = fmaf(bf2f(pv[i]), w[i][j], acc[i]);
    }
    ushort o[8];
    #pragma unroll
    for (int i = 0; i < 8; i++) {
        float s = acc[i];
        float sig = 1.f / (1.f + __expf(-s));
        o[i] = f2bf(s * sig);
    }
    *(uint4*)(xc + ((size_t)blk) * DIN + d0) = *(uint4*)o;
}

// ---------------- dt projection (K=32, x_dbl stride 64) + softplus -> delta (bf16) ----------------
#define DT_TILE_L 16
__global__ __launch_bounds__(256) void dt_softplus_kernel(
    const float* __restrict__ x_dbl, const float* __restrict__ dtw,
    const float* __restrict__ dtb, ushort* __restrict__ delta)
{
    __shared__ float xs[DT_TILE_L][32];
    long row0 = (long)blockIdx.x * DT_TILE_L;
    int tid = threadIdx.x;
    for (int i = tid; i < DT_TILE_L * 32; i += 256) {
        int r = i >> 5, k = i & 31;
        xs[r][k] = x_dbl[(row0 + r) * 64 + k];
    }
    __syncthreads();
    for (int d = tid; d < DIN; d += 256) {
        float w[32];
        #pragma unroll
        for (int k = 0; k < 32; k++) w[k] = dtw[d * 32 + k];
        float bias = dtb[d];
        for (int r = 0; r < DT_TILE_L; r++) {
            float s = bias;
            #pragma unroll
            for (int k = 0; k < 32; k++) s = fmaf(xs[r][k], w[k], s);
            float sp = fmaxf(s, 0.f) + log1pf(__expf(-fabsf(s)));
            delta[(row0 + r) * DIN + d] = f2bf(sp);
        }
    }
}

// ---------------- per-chunk delta sums (bf16 in, vectorized x8) ----------------
__global__ __launch_bounds__(64) void chunk_sum_kernel(
    const ushort* __restrict__ delta, float* __restrict__ csum)
{
    int blk = blockIdx.x;            // b(8) x c(48) x dblk(2)
    int dblk = blk & 1;
    int c = (blk >> 1) % NCHUNK;
    int b = blk / (2 * NCHUNK);
    int d0 = dblk * 512 + threadIdx.x * 8;
    float s[8] = {};
    for (int t = c * CHUNK; t < (c + 1) * CHUNK; ++t) {
        uint4 v = *(const uint4*)(delta + ((size_t)(b * L_TOT + t)) * DIN + d0);
        const ushort* pv = (const ushort*)&v;
        #pragma unroll
        for (int i = 0; i < 8; i++) s[i] += bf2f(pv[i]);
    }
    float* o = csum + ((size_t)(b * NCHUNK + c)) * DIN + d0;
    #pragma unroll
    for (int i = 0; i < 8; i++) o[i] = s[i];
}

// ---------------- chunked suffix-scan reduction, C_last folded in ----------------
__global__ __launch_bounds__(64) void scan_chunk_kernel(
    const ushort* __restrict__ delta, const ushort* __restrict__ xc,
    const float* __restrict__ x_dbl, const float* __restrict__ A_log,
    const float* __restrict__ csum, float* __restrict__ pacc_y)
{
    int blk = blockIdx.x;            // b(8) x c(48) x dblk(16)
    int dblk = blk & 15;
    int c = (blk >> 4) % NCHUNK;
    int b = blk / (16 * NCHUNK);
    int d = dblk * 64 + threadIdx.x;
    long pidx = ((long)(b * NCHUNK + c)) * DIN + d;

    float S = 0.f;
    bool dead = false;
    for (int cc = c + 1; cc < NCHUNK; ++cc) {
        S += csum[((long)(b * NCHUNK + cc)) * DIN + d];
        if (__all(S > S_CUT)) { dead = true; break; }
    }
    if (dead) { pacc_y[pidx] = 0.f; return; }

    float a[NST];
    #pragma unroll
    for (int n = 0; n < NST; n++) a[n] = -__expf(A_log[d * NST + n]);
    const float* xdl = x_dbl + ((size_t)(b * L_TOT + (L_TOT - 1))) * 64;
    float Cl[NST];
    #pragma unroll
    for (int n = 0; n < NST; n++) Cl[n] = xdl[40 + n];

    float acc = 0.f;
    int t0 = c * CHUNK;
    for (int t = t0 + CHUNK - 1; t >= t0; --t) {
        size_t idx = ((size_t)(b * L_TOT + t)) * DIN + d;
        float dl = bf2f(delta[idx]);
        float u = bf2f(xc[idx]);
        const float* xb = x_dbl + ((size_t)(b * L_TOT + t)) * 64 + 32;
        float w = dl * u;
        #pragma unroll
        for (int n = 0; n < NST; n++)
            acc = fmaf(w * xb[n] * Cl[n], __expf(a[n] * S), acc);
        S += dl;
        if (((t & 7) == 0) && __all(S > S_CUT)) break;
    }
    pacc_y[pidx] = acc;
}

// ---------------- finalize: y_last[b,d] ----------------
__global__ __launch_bounds__(256) void scan_finalize_kernel(
    const float* __restrict__ pacc_y, const float* __restrict__ x_dbl,
    const ushort* __restrict__ delta, const ushort* __restrict__ xc,
    const float* __restrict__ Dp, const float* __restrict__ z_last,
    float* __restrict__ y_last)
{
    int g = blockIdx.x * 256 + threadIdx.x;    // 8192
    int b = g >> 10;
    int d = g & 1023;
    const float* xd = x_dbl + ((size_t)(b * L_TOT + (L_TOT - 1))) * 64;
    float y = 0.f;
    for (int c = 0; c < NCHUNK; c++)
        y += pacc_y[((long)(b * NCHUNK + c)) * DIN + d];
    float bc = 0.f;
    #pragma unroll
    for (int n = 0; n < NST; n++) bc += xd[32 + n] * xd[40 + n];
    size_t idxL = ((size_t)(b * L_TOT + (L_TOT - 1))) * DIN + d;
    float dL = bf2f(delta[idxL]), uL = bf2f(xc[idxL]);
    y += dL * uL * bc;            // backward-scan first step at original l=L-1
    y += 2.f * uL * Dp[d];        // u*Dp from both directions
    float z = z_last[g];
    y_last[g] = y * (z / (1.f + __expf(-z)));
}

// ---------------- out_proj(last) + LayerNorm + ReLU + head ----------------
__global__ __launch_bounds__(256) void head_kernel(
    const float* __restrict__ y_last, const float* __restrict__ out_proj_w,
    const float* __restrict__ ln_g, const float* __restrict__ ln_b,
    const float* __restrict__ head_w, const float* __restrict__ head_b,
    float* __restrict__ out)
{
    int b = blockIdx.x;
    int tid = threadIdx.x;
    __shared__ float ys[DIN];
    __shared__ float h[DM];
    __shared__ float red[256];
    for (int i = tid; i < DIN; i += 256) ys[i] = y_last[b * DIN + i];
    __syncthreads();
    for (int e = tid; e < DM; e += 256) {
        const float* w = out_proj_w + (size_t)e * DIN;
        float s = 0.f;
        for (int k = 0; k < DIN; k += 4) {
            float4 wv = *(const float4*)(w + k);
            s = fmaf(ys[k], wv.x, s); s = fmaf(ys[k + 1], wv.y, s);
            s = fmaf(ys[k + 2], wv.z, s); s = fmaf(ys[k + 3], wv.w, s);
        }
        h[e] = s;
    }
    __syncthreads();
    red[tid] = h[tid] + h[tid + 256];
    __syncthreads();
    for (int s = 128; s > 0; s >>= 1) { if (tid < s) red[tid] += red[tid + s]; __syncthreads(); }
    float mu = red[0] / (float)DM;
    __syncthreads();
    float d0 = h[tid] - mu, d1 = h[tid + 256] - mu;
    red[tid] = d0 * d0 + d1 * d1;
    __syncthreads();
    for (int s = 128; s > 0; s >>= 1) { if (tid < s) red[tid] += red[tid + s]; __syncthreads(); }
    float inv = 1.f / sqrtf(red[0] / (float)DM + 1e-5f);
    __syncthreads();
    for (int e = tid; e < DM; e += 256) {
        float v = (h[e] - mu) * inv * ln_g[e] + ln_b[e];
        h[e] = fmaxf(v, 0.f);
    }
    __syncthreads();
    if (tid < 160) {
        int e2 = tid >> 4, pp = tid & 15;
        float s = 0.f;
        for (int k = pp * 32; k < pp * 32 + 32; k++) s += h[k] * head_w[e2 * DM + k];
        red[tid] = s;
    }
    __syncthreads();
    if (tid < 10) {
        float s = 0.f;
        for (int i = 0; i < 16; i++) s += red[tid * 16 + i];
        out[b * 10 + tid] = s + head_b[tid];
    }
}

extern "C" void kernel_launch(void* const* d_in, const int* in_sizes, int n_in,
                              void* d_out, int out_size, void* d_ws, size_t ws_size,
                              hipStream_t stream) {
    const float* feat0 = (const float*)d_in[0];
    const float* feat1 = (const float*)d_in[1];
    const float* feat2 = (const float*)d_in[2];
    const float* aw0 = (const float*)d_in[3];
    const float* ab0 = (const float*)d_in[4];
    const float* aw1 = (const float*)d_in[5];
    const float* ab1 = (const float*)d_in[6];
    const float* aw2 = (const float*)d_in[7];
    const float* ab2 = (const float*)d_in[8];
    const float* in_proj_w = (const float*)d_in[9];
    const float* conv_w = (const float*)d_in[10];
    const float* conv_b = (const float*)d_in[11];
    const float* x_proj_w = (const float*)d_in[12];
    const float* dt_proj_w = (const float*)d_in[13];
    const float* dt_proj_b = (const float*)d_in[14];
    const float* A_log = (const float*)d_in[15];
    // d_in[16] = A_b_log: unused (backward scan's dA multiplies h0=0)
    const float* Dp = (const float*)d_in[17];
    const float* out_proj_w = (const float*)d_in[18];
    const float* ln_g = (const float*)d_in[19];
    const float* ln_b = (const float*)d_in[20];
    const float* head_w = (const float*)d_in[21];
    const float* head_b = (const float*)d_in[22];
    float* out = (float*)d_out;

    char* ws = (char*)d_ws;
    ushort* xh_b  = (ushort*)(ws);                    // 50331648 B ; reused by delta
    ushort* xc_b  = (ushort*)(ws + 50331648);         // 50331648 B
    ushort* x_b   = (ushort*)(ws + 100663296);        // 25165824 B
    ushort* f0_b  = (ushort*)(ws + 125829120);        // 12582912 B
    ushort* f1_b  = (ushort*)(ws + 138412032);        // 16777216 B
    ushort* f2_b  = (ushort*)(ws + 155189248);        //  8388608 B
    ushort* w0_b  = (ushort*)(ws + 163577856);        //   786432 B
    ushort* w1_b  = (ushort*)(ws + 164364288);        //  1048576 B
    ushort* w2_b  = (ushort*)(ws + 165412864);        //   524288 B
    ushort* ipw_b = (ushort*)(ws + 165937152);        //  1048576 B (rows 0..1023)
    ushort* xpw_b = (ushort*)(ws + 166985728);        //   131072 B (64x1024 padded)
    float*  x_dbl = (float*)(ws + 167116800);         //  6291456 B (24576 x 64, stride 64)
    char* tail = ws + 173408256;
    float* z_last = (float*)tail;                     // 32768
    float* y_last = (float*)(tail + 32768);           // 32768
    float* csum   = (float*)(tail + 65536);           // 1572864
    float* pacc_y = (float*)(tail + 65536 + 1572864); // 1572864
    ushort* delta_b = xh_b;                           // xh dead after conv

    // 0. fp32 -> bf16 conversions (feats + all GEMM weights, x_proj padded to 64 rows)
    convert_kernel<<<10080, 256, 0, stream>>>(feat0, feat1, feat2, aw0, aw1, aw2,
                                              in_proj_w, x_proj_w,
                                              f0_b, f1_b, f2_b, w0_b, w1_b, w2_b,
                                              ipw_b, xpw_b);

    // 1. feature projections -> x bf16 (B, 3072, 512); segment s -> rows [s*1024,(s+1)*1024)
    gemm_mfma<128, 128, 2, 2, 4, 4, true><<<dim3(64, 4), 256, 0, stream>>>(
        f0_b, 768, w0_b, 768, x_b, DM, 8192, 768, ab0, 1024, (long)L_TOT * DM, 0L * 1024 * DM);
    gemm_mfma<128, 128, 2, 2, 4, 4, true><<<dim3(64, 4), 256, 0, stream>>>(
        f1_b, 1024, w1_b, 1024, x_b, DM, 8192, 1024, ab1, 1024, (long)L_TOT * DM, 1L * 1024 * DM);
    gemm_mfma<128, 128, 2, 2, 4, 4, true><<<dim3(64, 4), 256, 0, stream>>>(
        f2_b, 512, w2_b, 512, x_b, DM, 8192, 512, ab2, 1024, (long)L_TOT * DM, 2L * 1024 * DM);

    // 2. in_proj (xh half) -> xh bf16; z at last position only
    gemm_mfma<128, 128, 2, 2, 4, 4, true><<<dim3(192, 8), 256, 0, stream>>>(
        x_b, DM, ipw_b, DM, xh_b, DIN, NB * L_TOT, DM, nullptr, NB * L_TOT, 0, 0);
    z_last_kernel<<<NB, 256, 0, stream>>>(x_b, in_proj_w, z_last);

    // 3. causal depthwise conv + silu -> xc bf16
    conv_silu_kernel<<<NB * L_TOT, 128, 0, stream>>>(xh_b, conv_w, conv_b, xc_b);

    // 4. x_dbl = xc @ x_proj_w^T (N padded to 64) -> fp32, stride 64
    gemm_mfma<64, 64, 4, 1, 1, 4, false><<<dim3(384, 1), 256, 0, stream>>>(
        xc_b, DIN, xpw_b, DIN, x_dbl, 64, NB * L_TOT, DIN, nullptr, NB * L_TOT, 0, 0);

    // 5. delta = softplus(x_dbl[:, :32] @ dt_proj_w^T + dt_proj_b) -> bf16 (overwrites xh)
    dt_softplus_kernel<<<NB * L_TOT / DT_TILE_L, 256, 0, stream>>>(x_dbl, dt_proj_w, dt_proj_b, delta_b);

    // 6. scan: chunk sums -> chunked suffix reduction (early-exit) -> finalize
    chunk_sum_kernel<<<NB * NCHUNK * 2, 64, 0, stream>>>(delta_b, csum);
    scan_chunk_kernel<<<NB * NCHUNK * 16, 64, 0, stream>>>(delta_b, xc_b, x_dbl, A_log, csum, pacc_y);
    scan_finalize_kernel<<<NB * DIN / 256, 256, 0, stream>>>(pacc_y, x_dbl, delta_b, xc_b, Dp, z_last, y_last);

    // 7. out_proj(last) + LN + ReLU + head
    head_kernel<<<NB, 256, 0, stream>>>(y_last, out_proj_w, ln_g, ln_b, head_w, head_b, out);
}

// Round 5
// 507.928 us; speedup vs baseline: 3.3538x; 1.0954x over previous
//
#include <hip/hip_runtime.h>

#define L_TOT 3072
#define DM 512
#define DIN 1024
#define NST 8
#define NB 8
#define NCHUNK 48
#define CHUNK 64
#define S_CUT 18.0f

typedef __attribute__((ext_vector_type(8))) short bf16x8;
typedef __attribute__((ext_vector_type(4))) float f32x4;

__device__ __forceinline__ float bf2f(ushort u) {
    union { uint i; float f; } c; c.i = ((uint)u) << 16; return c.f;
}
__device__ __forceinline__ ushort f2bf(float f) {
    union { float f; uint i; } c; c.f = f;
    uint x = c.i;
    uint r = x + 0x7fffu + ((x >> 16) & 1u);
    return (ushort)(r >> 16);
}
__device__ __forceinline__ void async16(const void* g, void* l) {
    __builtin_amdgcn_global_load_lds((const __attribute__((address_space(1))) char*)g,
                                     (__attribute__((address_space(3))) char*)l, 16, 0, 0);
}

// ---------------- fp32 -> bf16 conversion (fused, all tensors) ----------------
__device__ __forceinline__ void cvt8(const float* s, ushort* d) {
    float4 a = *(const float4*)s;
    float4 b = *(const float4*)(s + 4);
    ushort o[8] = {f2bf(a.x), f2bf(a.y), f2bf(a.z), f2bf(a.w),
                   f2bf(b.x), f2bf(b.y), f2bf(b.z), f2bf(b.w)};
    *(uint4*)d = *(uint4*)o;
}
__device__ __forceinline__ void cvt8s(const float* s, ushort* dh, ushort* dl) {
    float4 a = *(const float4*)s;
    float4 b = *(const float4*)(s + 4);
    float v[8] = {a.x, a.y, a.z, a.w, b.x, b.y, b.z, b.w};
    ushort oh[8], ol[8];
    #pragma unroll
    for (int i = 0; i < 8; i++) {
        oh[i] = f2bf(v[i]);
        ol[i] = f2bf(v[i] - bf2f(oh[i]));
    }
    *(uint4*)dh = *(uint4*)oh;
    *(uint4*)dl = *(uint4*)ol;
}

// segments (elements): f0 6291456 | f1 8388608 | f2 4194304 | w0 393216 | w1 524288
// | w2 262144 | ipw 524288 | xpw 65536 (64x1024 padded) | dtw 32768 (hi+lo same pass)
// total 20676608 elems / 8 per thread / 256 per block = 10096 blocks exactly.
__global__ __launch_bounds__(256) void convert_kernel(
    const float* __restrict__ f0, const float* __restrict__ f1, const float* __restrict__ f2,
    const float* __restrict__ w0, const float* __restrict__ w1, const float* __restrict__ w2,
    const float* __restrict__ ipw, const float* __restrict__ xpw, const float* __restrict__ dtw,
    ushort* __restrict__ d_f0, ushort* __restrict__ d_f1, ushort* __restrict__ d_f2,
    ushort* __restrict__ d_w0, ushort* __restrict__ d_w1, ushort* __restrict__ d_w2,
    ushort* __restrict__ d_ipw, ushort* __restrict__ d_xpw,
    ushort* __restrict__ d_dtw, ushort* __restrict__ d_dtwlo)
{
    long e = ((long)blockIdx.x * 256 + threadIdx.x) * 8;
    if (e < 6291456)  { cvt8(f0 + e, d_f0 + e); return; }
    e -= 6291456;
    if (e < 8388608)  { cvt8(f1 + e, d_f1 + e); return; }
    e -= 8388608;
    if (e < 4194304)  { cvt8(f2 + e, d_f2 + e); return; }
    e -= 4194304;
    if (e < 393216)   { cvt8(w0 + e, d_w0 + e); return; }
    e -= 393216;
    if (e < 524288)   { cvt8(w1 + e, d_w1 + e); return; }
    e -= 524288;
    if (e < 262144)   { cvt8(w2 + e, d_w2 + e); return; }
    e -= 262144;
    if (e < 524288)   { cvt8(ipw + e, d_ipw + e); return; }
    e -= 524288;
    if (e < 65536) {  // x_proj_w padded 48x1024 -> 64x1024 (zero rows 48..63); 65536 ELEMENTS
        int row = (int)(e >> 10), col = (int)(e & 1023);
        if (row < 48) cvt8(xpw + row * 1024 + col, d_xpw + e);
        else { uint4 z = make_uint4(0, 0, 0, 0); *(uint4*)(d_xpw + e) = z; }
        return;
    }
    e -= 65536;
    if (e < 32768)    { cvt8s(dtw + e, d_dtw + e, d_dtwlo + e); return; }
}

// ---------------- bf16 MFMA GEMM: C = A(MxK) * Bw(NxK)^T ----------------
// EPI=1: bf16 out (+bias), concat row remap
// EPI=2: split: cols 0..31 -> bf16 hi C2 + bf16 lo C3 (stride 32); cols 32..47 -> fp32 C (stride 16)
template<int BM, int BN, int NWM, int NWN, int FM, int FN, int EPI>
__global__ __launch_bounds__(256) void gemm_mfma(
    const ushort* __restrict__ A, int lda,
    const ushort* __restrict__ Bw, int ldb,
    void* __restrict__ C, int ldc,
    int M, int K,
    const float* __restrict__ bias,
    int rows_per_batch, long out_batch_stride, long out_base,
    void* __restrict__ C2, void* __restrict__ C3)
{
    constexpr int BK = 32;
    __shared__ ushort As[BM * BK];
    __shared__ ushort Bs[BN * BK];
    int tid = threadIdx.x;
    int lane = tid & 63;
    int wid = tid >> 6;
    int bm = blockIdx.x * BM;
    int bn = blockIdx.y * BN;
    int wm = (wid / NWN) * FM * 16;
    int wn = (wid % NWN) * FN * 16;
    int trow = tid >> 2;              // staging: 4096B = 64 rows of 64B
    int tcol = (tid & 3) * 8;

    f32x4 zero = {0.f, 0.f, 0.f, 0.f};
    f32x4 acc[FM][FN];
    #pragma unroll
    for (int m = 0; m < FM; m++)
        #pragma unroll
        for (int n = 0; n < FN; n++) acc[m][n] = zero;

    constexpr int nA = BM * BK * 2 / 4096;
    constexpr int nB = BN * BK * 2 / 4096;

    for (int k0 = 0; k0 < K; k0 += BK) {
        __syncthreads();
        #pragma unroll
        for (int i = 0; i < nA; i++) {
            int row = i * 64 + trow;
            async16(A + (size_t)(bm + row) * lda + k0 + tcol, (char*)As + i * 4096 + tid * 16);
        }
        #pragma unroll
        for (int i = 0; i < nB; i++) {
            int row = i * 64 + trow;
            async16(Bw + (size_t)(bn + row) * ldb + k0 + tcol, (char*)Bs + i * 4096 + tid * 16);
        }
        __syncthreads();

        bf16x8 af[FM], bfr[FN];
        #pragma unroll
        for (int m = 0; m < FM; m++)
            af[m] = *(const bf16x8*)(As + (wm + m * 16 + (lane & 15)) * BK + (lane >> 4) * 8);
        #pragma unroll
        for (int n = 0; n < FN; n++)
            bfr[n] = *(const bf16x8*)(Bs + (wn + n * 16 + (lane & 15)) * BK + (lane >> 4) * 8);
        #pragma unroll
        for (int m = 0; m < FM; m++)
            #pragma unroll
            for (int n = 0; n < FN; n++)
                acc[m][n] = __builtin_amdgcn_mfma_f32_16x16x32_bf16(af[m], bfr[n], acc[m][n], 0, 0, 0);
    }

    if constexpr (EPI == 1) {
        #pragma unroll
        for (int m = 0; m < FM; m++) {
            int rbase = bm + wm + m * 16 + (lane >> 4) * 4;
            #pragma unroll
            for (int n = 0; n < FN; n++) {
                int c_ = bn + wn + n * 16 + (lane & 15);
                float bv = bias ? bias[c_] : 0.f;
                #pragma unroll
                for (int r = 0; r < 4; r++) {
                    int r_ = rbase + r;
                    long row_off = out_base + (long)(r_ / rows_per_batch) * out_batch_stride
                                 + (long)(r_ % rows_per_batch) * ldc;
                    ((ushort*)C)[row_off + c_] = f2bf(acc[m][n][r] + bv);
                }
            }
        }
    } else { // EPI == 2
        #pragma unroll
        for (int m = 0; m < FM; m++) {
            int rbase = bm + wm + m * 16 + (lane >> 4) * 4;
            #pragma unroll
            for (int n = 0; n < FN; n++) {
                int c_ = bn + wn + n * 16 + (lane & 15);
                #pragma unroll
                for (int r = 0; r < 4; r++) {
                    int r_ = rbase + r;
                    float v = acc[m][n][r];
                    if (c_ < 32) {
                        ushort h = f2bf(v);
                        ((ushort*)C2)[(size_t)r_ * 32 + c_] = h;
                        ((ushort*)C3)[(size_t)r_ * 32 + c_] = f2bf(v - bf2f(h));
                    } else if (c_ < 48) {
                        ((float*)C)[(size_t)r_ * 16 + (c_ - 32)] = v;
                    }
                }
            }
        }
    }
}

// ---------------- dt GEMM (split-precision bf16 hi/lo) + softplus + fused csum ----------------
// delta = softplus(dt_in @ dtw^T + dtb); wave = exactly 64 rows = 1 chunk -> csum
__global__ __launch_bounds__(256) void dt_gemm_kernel(
    const ushort* __restrict__ Ahi, const ushort* __restrict__ Alo,   // 24576 x 32
    const ushort* __restrict__ Bhi, const ushort* __restrict__ Blo,   // 1024 x 32
    const float* __restrict__ bias,
    ushort* __restrict__ delta, float* __restrict__ csum)
{
    __shared__ ushort AsH[128 * 32];
    __shared__ ushort AsL[128 * 32];
    __shared__ ushort BsH[128 * 32];
    __shared__ ushort BsL[128 * 32];
    int tid = threadIdx.x;
    int lane = tid & 63;
    int wid = tid >> 6;
    int bm = blockIdx.x * 128;
    int bn = blockIdx.y * 128;
    int wm = (wid >> 1) * 64;
    int wn = (wid & 1) * 64;
    int trow = tid >> 2;
    int tcol = (tid & 3) * 8;

    #pragma unroll
    for (int i = 0; i < 2; i++) {
        int row = i * 64 + trow;
        async16(Ahi + (size_t)(bm + row) * 32 + tcol, (char*)AsH + i * 4096 + tid * 16);
        async16(Alo + (size_t)(bm + row) * 32 + tcol, (char*)AsL + i * 4096 + tid * 16);
        async16(Bhi + (size_t)(bn + row) * 32 + tcol, (char*)BsH + i * 4096 + tid * 16);
        async16(Blo + (size_t)(bn + row) * 32 + tcol, (char*)BsL + i * 4096 + tid * 16);
    }
    __syncthreads();

    f32x4 zero = {0.f, 0.f, 0.f, 0.f};
    f32x4 acc[4][4];
    #pragma unroll
    for (int m = 0; m < 4; m++)
        #pragma unroll
        for (int n = 0; n < 4; n++) acc[m][n] = zero;

    bf16x8 ah[4], al[4], bh[4], bl[4];
    #pragma unroll
    for (int m = 0; m < 4; m++) {
        int off = (wm + m * 16 + (lane & 15)) * 32 + (lane >> 4) * 8;
        ah[m] = *(const bf16x8*)(AsH + off);
        al[m] = *(const bf16x8*)(AsL + off);
    }
    #pragma unroll
    for (int n = 0; n < 4; n++) {
        int off = (wn + n * 16 + (lane & 15)) * 32 + (lane >> 4) * 8;
        bh[n] = *(const bf16x8*)(BsH + off);
        bl[n] = *(const bf16x8*)(BsL + off);
    }
    #pragma unroll
    for (int m = 0; m < 4; m++)
        #pragma unroll
        for (int n = 0; n < 4; n++) {
            acc[m][n] = __builtin_amdgcn_mfma_f32_16x16x32_bf16(al[m], bh[n], acc[m][n], 0, 0, 0);
            acc[m][n] = __builtin_amdgcn_mfma_f32_16x16x32_bf16(ah[m], bl[n], acc[m][n], 0, 0, 0);
            acc[m][n] = __builtin_amdgcn_mfma_f32_16x16x32_bf16(ah[m], bh[n], acc[m][n], 0, 0, 0);
        }

    #pragma unroll
    for (int n = 0; n < 4; n++) {
        int c_ = bn + wn + n * 16 + (lane & 15);
        float bv = bias[c_];
        float s = 0.f;
        #pragma unroll
        for (int m = 0; m < 4; m++) {
            int rbase = bm + wm + m * 16 + (lane >> 4) * 4;
            #pragma unroll
            for (int r = 0; r < 4; r++) {
                float v = acc[m][n][r] + bv;
                float sp = fmaxf(v, 0.f) + log1pf(__expf(-fabsf(v)));
                ushort ob = f2bf(sp);
                delta[(size_t)(rbase + r) * DIN + c_] = ob;
                s += bf2f(ob);
            }
        }
        s += __shfl_xor(s, 16, 64);
        s += __shfl_xor(s, 32, 64);
        if ((lane >> 4) == 0) {
            int grow = bm + wm;
            int bb = grow / L_TOT;
            int cc = (grow % L_TOT) >> 6;
            csum[((size_t)(bb * NCHUNK + cc)) * DIN + c_] = s;
        }
    }
}

// ---------------- z at last position only (x in bf16) ----------------
__global__ __launch_bounds__(256) void z_last_kernel(
    const ushort* __restrict__ x, const float* __restrict__ in_proj_w,
    float* __restrict__ z_last)
{
    int b = blockIdx.x;
    int tid = threadIdx.x;
    __shared__ float xs[DM];
    for (int i = tid; i < DM; i += 256)
        xs[i] = bf2f(x[((size_t)(b * L_TOT + (L_TOT - 1))) * DM + i]);
    __syncthreads();
    for (int d = tid; d < DIN; d += 256) {
        const float* w = in_proj_w + (size_t)(DIN + d) * DM;
        float s = 0.f;
        for (int k = 0; k < DM; k += 4) {
            float4 wv = *(const float4*)(w + k);
            s = fmaf(xs[k], wv.x, s); s = fmaf(xs[k + 1], wv.y, s);
            s = fmaf(xs[k + 2], wv.z, s); s = fmaf(xs[k + 3], wv.w, s);
        }
        z_last[b * DIN + d] = s;
    }
}

// ---------------- causal depthwise conv (k=4) + silu, bf16 in/out ----------------
__global__ __launch_bounds__(128) void conv_silu_kernel(
    const ushort* __restrict__ xh, const float* __restrict__ conv_w,
    const float* __restrict__ conv_b, ushort* __restrict__ xc)
{
    int blk = blockIdx.x;            // b*L + l
    int b = blk / L_TOT;
    int l = blk % L_TOT;
    int d0 = threadIdx.x * 8;
    float acc[8];
    {
        float4 b0 = *(const float4*)(conv_b + d0);
        float4 b1 = *(const float4*)(conv_b + d0 + 4);
        acc[0] = b0.x; acc[1] = b0.y; acc[2] = b0.z; acc[3] = b0.w;
        acc[4] = b1.x; acc[5] = b1.y; acc[6] = b1.z; acc[7] = b1.w;
    }
    float w[8][4];
    #pragma unroll
    for (int i = 0; i < 8; i++) {
        float4 wv = *(const float4*)(conv_w + (d0 + i) * 4);
        w[i][0] = wv.x; w[i][1] = wv.y; w[i][2] = wv.z; w[i][3] = wv.w;
    }
    #pragma unroll
    for (int j = 0; j < 4; j++) {
        int ls = l - 3 + j;
        if (ls < 0) continue;
        uint4 v = *(const uint4*)(xh + ((size_t)(b * L_TOT + ls)) * DIN + d0);
        const ushort* pv = (const ushort*)&v;
        #pragma unroll
        for (int i = 0; i < 8; i++)
            acc[i] = fmaf(bf2f(pv[i]), w[i][j], acc[i]);
    }
    ushort o[8];
    #pragma unroll
    for (int i = 0; i < 8; i++) {
        float s = acc[i];
        float sig = 1.f / (1.f + __expf(-s));
        o[i] = f2bf(s * sig);
    }
    *(uint4*)(xc + ((size_t)blk) * DIN + d0) = *(uint4*)o;
}

// ---------------- chunked suffix-scan reduction, C_last folded in ----------------
__global__ __launch_bounds__(64) void scan_chunk_kernel(
    const ushort* __restrict__ delta, const ushort* __restrict__ xc,
    const float* __restrict__ BC, const float* __restrict__ A_log,
    const float* __restrict__ csum, float* __restrict__ pacc_y)
{
    int blk = blockIdx.x;            // b(8) x c(48) x dblk(16)
    int dblk = blk & 15;
    int c = (blk >> 4) % NCHUNK;
    int b = blk / (16 * NCHUNK);
    int d = dblk * 64 + threadIdx.x;
    long pidx = ((long)(b * NCHUNK + c)) * DIN + d;

    float S = 0.f;
    bool dead = false;
    for (int cc = c + 1; cc < NCHUNK; ++cc) {
        S += csum[((long)(b * NCHUNK + cc)) * DIN + d];
        if (__all(S > S_CUT)) { dead = true; break; }
    }
    if (dead) { pacc_y[pidx] = 0.f; return; }

    float a[NST];
    #pragma unroll
    for (int n = 0; n < NST; n++) a[n] = -__expf(A_log[d * NST + n]);
    const float* bcL = BC + ((size_t)(b * L_TOT + (L_TOT - 1))) * 16;
    float Cl[NST];
    #pragma unroll
    for (int n = 0; n < NST; n++) Cl[n] = bcL[8 + n];

    float acc = 0.f;
    int t0 = c * CHUNK;
    for (int t = t0 + CHUNK - 1; t >= t0; --t) {
        size_t idx = ((size_t)(b * L_TOT + t)) * DIN + d;
        float dl = bf2f(delta[idx]);
        float u = bf2f(xc[idx]);
        const float* xb = BC + ((size_t)(b * L_TOT + t)) * 16;
        float w = dl * u;
        #pragma unroll
        for (int n = 0; n < NST; n++)
            acc = fmaf(w * xb[n] * Cl[n], __expf(a[n] * S), acc);
        S += dl;
        if (((t & 7) == 0) && __all(S > S_CUT)) break;
    }
    pacc_y[pidx] = acc;
}

// ---------------- finalize: y_last[b,d] ----------------
__global__ __launch_bounds__(256) void scan_finalize_kernel(
    const float* __restrict__ pacc_y, const float* __restrict__ BC,
    const ushort* __restrict__ delta, const ushort* __restrict__ xc,
    const float* __restrict__ Dp, const float* __restrict__ z_last,
    float* __restrict__ y_last)
{
    int g = blockIdx.x * 256 + threadIdx.x;    // 8192
    int b = g >> 10;
    int d = g & 1023;
    const float* xd = BC + ((size_t)(b * L_TOT + (L_TOT - 1))) * 16;
    float y = 0.f;
    for (int c = 0; c < NCHUNK; c++)
        y += pacc_y[((long)(b * NCHUNK + c)) * DIN + d];
    float bc = 0.f;
    #pragma unroll
    for (int n = 0; n < NST; n++) bc += xd[n] * xd[8 + n];
    size_t idxL = ((size_t)(b * L_TOT + (L_TOT - 1))) * DIN + d;
    float dL = bf2f(delta[idxL]), uL = bf2f(xc[idxL]);
    y += dL * uL * bc;            // backward-scan first step at original l=L-1
    y += 2.f * uL * Dp[d];        // u*Dp from both directions
    float z = z_last[g];
    y_last[g] = y * (z / (1.f + __expf(-z)));
}

// ---------------- out_proj(last) + LayerNorm + ReLU + head ----------------
__global__ __launch_bounds__(256) void head_kernel(
    const float* __restrict__ y_last, const float* __restrict__ out_proj_w,
    const float* __restrict__ ln_g, const float* __restrict__ ln_b,
    const float* __restrict__ head_w, const float* __restrict__ head_b,
    float* __restrict__ out)
{
    int b = blockIdx.x;
    int tid = threadIdx.x;
    __shared__ float ys[DIN];
    __shared__ float h[DM];
    __shared__ float red[256];
    for (int i = tid; i < DIN; i += 256) ys[i] = y_last[b * DIN + i];
    __syncthreads();
    for (int e = tid; e < DM; e += 256) {
        const float* w = out_proj_w + (size_t)e * DIN;
        float s = 0.f;
        for (int k = 0; k < DIN; k += 4) {
            float4 wv = *(const float4*)(w + k);
            s = fmaf(ys[k], wv.x, s); s = fmaf(ys[k + 1], wv.y, s);
            s = fmaf(ys[k + 2], wv.z, s); s = fmaf(ys[k + 3], wv.w, s);
        }
        h[e] = s;
    }
    __syncthreads();
    red[tid] = h[tid] + h[tid + 256];
    __syncthreads();
    for (int s = 128; s > 0; s >>= 1) { if (tid < s) red[tid] += red[tid + s]; __syncthreads(); }
    float mu = red[0] / (float)DM;
    __syncthreads();
    float d0 = h[tid] - mu, d1 = h[tid + 256] - mu;
    red[tid] = d0 * d0 + d1 * d1;
    __syncthreads();
    for (int s = 128; s > 0; s >>= 1) { if (tid < s) red[tid] += red[tid + s]; __syncthreads(); }
    float inv = 1.f / sqrtf(red[0] / (float)DM + 1e-5f);
    __syncthreads();
    for (int e = tid; e < DM; e += 256) {
        float v = (h[e] - mu) * inv * ln_g[e] + ln_b[e];
        h[e] = fmaxf(v, 0.f);
    }
    __syncthreads();
    if (tid < 160) {
        int e2 = tid >> 4, pp = tid & 15;
        float s = 0.f;
        for (int k = pp * 32; k < pp * 32 + 32; k++) s += h[k] * head_w[e2 * DM + k];
        red[tid] = s;
    }
    __syncthreads();
    if (tid < 10) {
        float s = 0.f;
        for (int i = 0; i < 16; i++) s += red[tid * 16 + i];
        out[b * 10 + tid] = s + head_b[tid];
    }
}

extern "C" void kernel_launch(void* const* d_in, const int* in_sizes, int n_in,
                              void* d_out, int out_size, void* d_ws, size_t ws_size,
                              hipStream_t stream) {
    const float* feat0 = (const float*)d_in[0];
    const float* feat1 = (const float*)d_in[1];
    const float* feat2 = (const float*)d_in[2];
    const float* aw0 = (const float*)d_in[3];
    const float* ab0 = (const float*)d_in[4];
    const float* aw1 = (const float*)d_in[5];
    const float* ab1 = (const float*)d_in[6];
    const float* aw2 = (const float*)d_in[7];
    const float* ab2 = (const float*)d_in[8];
    const float* in_proj_w = (const float*)d_in[9];
    const float* conv_w = (const float*)d_in[10];
    const float* conv_b = (const float*)d_in[11];
    const float* x_proj_w = (const float*)d_in[12];
    const float* dt_proj_w = (const float*)d_in[13];
    const float* dt_proj_b = (const float*)d_in[14];
    const float* A_log = (const float*)d_in[15];
    // d_in[16] = A_b_log: unused (backward scan's dA multiplies h0=0)
    const float* Dp = (const float*)d_in[17];
    const float* out_proj_w = (const float*)d_in[18];
    const float* ln_g = (const float*)d_in[19];
    const float* ln_b = (const float*)d_in[20];
    const float* head_w = (const float*)d_in[21];
    const float* head_b = (const float*)d_in[22];
    float* out = (float*)d_out;

    char* ws = (char*)d_ws;
    ushort* xh_b    = (ushort*)(ws);                  // 50331648 B ; reused by delta
    ushort* xc_b    = (ushort*)(ws + 50331648);       // 50331648 B
    ushort* x_b     = (ushort*)(ws + 100663296);      // 25165824 B
    ushort* f0_b    = (ushort*)(ws + 125829120);      // 12582912 B
    ushort* f1_b    = (ushort*)(ws + 138412032);      // 16777216 B
    ushort* f2_b    = (ushort*)(ws + 155189248);      //  8388608 B
    ushort* w0_b    = (ushort*)(ws + 163577856);      //   786432 B
    ushort* w1_b    = (ushort*)(ws + 164364288);      //  1048576 B
    ushort* w2_b    = (ushort*)(ws + 165412864);      //   524288 B
    ushort* ipw_b   = (ushort*)(ws + 165937152);      //  1048576 B
    ushort* xpw_b   = (ushort*)(ws + 166985728);      //   131072 B (64x1024 padded)
    ushort* dtw_b   = (ushort*)(ws + 167116800);      //    65536 B (1024x32 hi)
    ushort* dtwlo_b = (ushort*)(ws + 167182336);      //    65536 B (1024x32 lo)
    ushort* dtin_b  = (ushort*)(ws + 167247872);      //  1572864 B (24576x32 hi)
    ushort* dtinlo_b= (ushort*)(ws + 168820736);      //  1572864 B (24576x32 lo)
    float*  BC      = (float*)(ws + 170393600);       //  1572864 B (24576x16: B|C)
    char* tail = ws + 171966464;
    float* z_last = (float*)tail;                     // 32768
    float* y_last = (float*)(tail + 32768);           // 32768
    float* csum   = (float*)(tail + 65536);           // 1572864
    float* pacc_y = (float*)(tail + 65536 + 1572864); // 1572864
    ushort* delta_b = xh_b;                           // xh dead after conv

    // 0. fp32 -> bf16 conversions
    convert_kernel<<<10096, 256, 0, stream>>>(feat0, feat1, feat2, aw0, aw1, aw2,
                                              in_proj_w, x_proj_w, dt_proj_w,
                                              f0_b, f1_b, f2_b, w0_b, w1_b, w2_b,
                                              ipw_b, xpw_b, dtw_b, dtwlo_b);

    // 1. feature projections -> x bf16 (B, 3072, 512)
    gemm_mfma<128, 128, 2, 2, 4, 4, 1><<<dim3(64, 4), 256, 0, stream>>>(
        f0_b, 768, w0_b, 768, x_b, DM, 8192, 768, ab0, 1024, (long)L_TOT * DM, 0L * 1024 * DM,
        nullptr, nullptr);
    gemm_mfma<128, 128, 2, 2, 4, 4, 1><<<dim3(64, 4), 256, 0, stream>>>(
        f1_b, 1024, w1_b, 1024, x_b, DM, 8192, 1024, ab1, 1024, (long)L_TOT * DM, 1L * 1024 * DM,
        nullptr, nullptr);
    gemm_mfma<128, 128, 2, 2, 4, 4, 1><<<dim3(64, 4), 256, 0, stream>>>(
        f2_b, 512, w2_b, 512, x_b, DM, 8192, 512, ab2, 1024, (long)L_TOT * DM, 2L * 1024 * DM,
        nullptr, nullptr);

    // 2. in_proj (xh half) -> xh bf16; z at last position only
    gemm_mfma<128, 128, 2, 2, 4, 4, 1><<<dim3(192, 8), 256, 0, stream>>>(
        x_b, DM, ipw_b, DM, xh_b, DIN, NB * L_TOT, DM, nullptr, NB * L_TOT, 0, 0,
        nullptr, nullptr);
    z_last_kernel<<<NB, 256, 0, stream>>>(x_b, in_proj_w, z_last);

    // 3. causal depthwise conv + silu -> xc bf16
    conv_silu_kernel<<<NB * L_TOT, 128, 0, stream>>>(xh_b, conv_w, conv_b, xc_b);

    // 4. x_dbl GEMM split epilogue: dt_in hi/lo (bf16, stride 32) + BC (fp32, stride 16)
    gemm_mfma<64, 64, 4, 1, 1, 4, 2><<<dim3(384, 1), 256, 0, stream>>>(
        xc_b, DIN, xpw_b, DIN, BC, 16, NB * L_TOT, DIN, nullptr, NB * L_TOT, 0, 0,
        dtin_b, dtinlo_b);

    // 5. delta = softplus(dt_in @ dt_proj_w^T + dtb) split-precision -> bf16 + fused csum
    dt_gemm_kernel<<<dim3(192, 8), 256, 0, stream>>>(
        dtin_b, dtinlo_b, dtw_b, dtwlo_b, dt_proj_b, delta_b, csum);

    // 6. scan: chunked suffix reduction (early-exit) -> finalize
    scan_chunk_kernel<<<NB * NCHUNK * 16, 64, 0, stream>>>(delta_b, xc_b, BC, A_log, csum, pacc_y);
    scan_finalize_kernel<<<NB * DIN / 256, 256, 0, stream>>>(pacc_y, BC, delta_b, xc_b, Dp, z_last, y_last);

    // 7. out_proj(last) + LN + ReLU + head
    head_kernel<<<NB, 256, 0, stream>>>(y_last, out_proj_w, ln_g, ln_b, head_w, head_b, out);
}